// Round 6
// baseline (8165.006 us; speedup 1.0000x reference)
//
#include <hip/hip_runtime.h>

#define TT 336
#define BB 256
#define DD 128
#define HH 1024
#define TD 43008     // T*D
#define BBHH 262144  // B*H elements

// B-pack geometry (ushort units)
#define SSU0 20480u     // layer0 wave stream: 10 ks * 4 ni * 512
#define SSU1 32768u     // layer1 wave stream: 16 ks * 4 ni * 512
#define LBU1 5242880u   // layer1 base = 32 ntiles * 8 slots * SSU0

typedef __attribute__((ext_vector_type(8))) short short8;
typedef __attribute__((ext_vector_type(8))) unsigned short ushort8;
typedef __attribute__((ext_vector_type(4))) unsigned short ushort4v;
typedef __attribute__((ext_vector_type(4))) float floatx4;

// ---- workspace layout (bytes) ----
#define OFF_CNT 0u          // 4 barrier counters, 256 B apart
#define OFF_B1P 4096u       // 16 KB permuted bias
#define OFF_B2P 20480u
#define OFF_H1  65536u      // 2 bufs x 512 KB bf16 (plain linear)
#define OFF_H2  1114112u
#define OFF_X   2162688u    // 22,020,096 (plain bf16)
#define OFF_BP  24182784u   // fragment-linear weight pack, 27,262,976
// end = 51,445,760

static __device__ __forceinline__ unsigned short f2bf(float f) {
  unsigned int x = __float_as_uint(f);
  x += 0x7fffu + ((x >> 16) & 1u);   // RNE
  return (unsigned short)(x >> 16);
}
static __device__ __forceinline__ float bf2f(unsigned short u) {
  return __uint_as_float(((unsigned int)u) << 16);
}
static __device__ __forceinline__ float sigm(float x) {
  return 1.f / (1.f + __expf(-x));
}
static __device__ __forceinline__ float tanh_fast(float x) {
  float ax = fabsf(x);
  float e = __expf(-2.f * ax);
  float t = (1.f - e) / (1.f + e);
  return x < 0.f ? -t : t;
}

// -------- init: zero counters + h bufs [0, OFF_X) + d_out -----------------
__global__ __launch_bounds__(256) void init_zero(float* out, uint4* span, long n16) {
  long i = (long)blockIdx.x * 256 + threadIdx.x;
  if (i < n16) span[i] = make_uint4(0u, 0u, 0u, 0u);
  if (i == 0) out[0] = 0.f;
}

// ------- features fp32 -> bf16 (plain linear) -----------------------------
__global__ __launch_bounds__(256) void feat2bf(const float* __restrict__ in,
                                               unsigned short* __restrict__ out, long nq) {
  long Q = (long)blockIdx.x * 256 + threadIdx.x;
  if (Q >= nq) return;
  const floatx4* pp = (const floatx4*)(in + Q * 8);
  floatx4 a = pp[0], c = pp[1];
  ushort8 v;
  #pragma unroll
  for (int q = 0; q < 4; ++q) { v[q] = f2bf(a[q]); v[4 + q] = f2bf(c[q]); }
  *(ushort8*)(out + Q * 8) = v;
}

// ---- pack W (K x 4096 f32) into fragment-linear bf16 ---------------------
// (unchanged from R5 — verified) gate-interleave n' = (n&1023)*4 + (n>>10);
// layer0 K padded 1152->1280 with zeros.
__global__ __launch_bounds__(256) void bpack(const float* __restrict__ W1,
                                             const float* __restrict__ W2,
                                             unsigned short* __restrict__ out) {
  __shared__ unsigned short tile[64][72];
  int bid = blockIdx.x, t = threadIdx.x;
  int L, tk, tn;
  if (bid < 1280) { L = 0; tk = bid % 20; tn = bid / 20; }
  else            { L = 1; tk = (bid - 1280) % 32; tn = (bid - 1280) / 32; }
  const float* W = L ? W2 : W1;
  int KG = L ? 512 : 320;
  int k0 = tk * 64, n0p = tn * 64;
  int g = k0 / KG;
  int ksg0 = (k0 - g * KG) >> 5;
  int ntile = n0p >> 7, wn = (n0p >> 6) & 1;
  unsigned int SSu = L ? SSU1 : SSU0;
  unsigned int base = (L ? LBU1 : 0u) + ntile * 8u * SSu + (g * 2 + wn) * SSu;

  #pragma unroll
  for (int i = 0; i < 16; ++i) {
    int idx = i * 256 + t;
    int kk = idx >> 6, nn = idx & 63;
    int np = n0p + nn;
    int norig = ((np & 3) << 10) + (np >> 2);
    float v = 0.f;
    if (!(L == 0 && k0 + kk >= 1152)) v = W[(size_t)(k0 + kk) * 4096 + norig];
    tile[kk][nn] = f2bf(v);
  }
  __syncthreads();
  int t64 = t & 63;
  #pragma unroll
  for (int pass = 0; pass < 2; ++pass) {
    int f = (t >> 6) + pass * 4;
    int ksl = f >> 2, ni = f & 3;
    ushort8 v;
    #pragma unroll
    for (int j = 0; j < 8; ++j)
      v[j] = tile[ksl * 32 + ((t64 >> 4) << 3) + j][ni * 16 + (t64 & 15)];
    *(ushort8*)(out + base + (unsigned)((ksg0 + ksl) * 4 + ni) * 512u + t64 * 8) = v;
  }
}

// ---- permute biases: bp[u*4+g] = b[g*1024+u] -----------------------------
__global__ __launch_bounds__(256) void bias_perm(const float* __restrict__ b1,
                                                 const float* __restrict__ b2,
                                                 float* __restrict__ b1p,
                                                 float* __restrict__ b2p) {
  int idx = blockIdx.x * 256 + threadIdx.x;
  const float* src = (idx < 4096) ? b1 : b2;
  float* dst = (idx < 4096) ? b1p : b2p;
  int n = idx & 4095;
  dst[n] = src[(n & 3) * 1024 + (n >> 2)];
}

// ---------------- persistent fused LSTM (no fences, L2-preserving) --------
// 256 blocks x 512 thr (8 waves, 2/SIMD), 1 block/CU. layer=bid>>7.
// Block tile 64m x 128n'; 4 k-groups x 2 waves, wave tile 64m x 64n.
// Weights: plain loads (L2-resident all 337 phases). h: agent-scope relaxed
// atomic 8B loads/stores (served at MALL; no cache invalidation needed).
// c-state in registers. Per-mtile 64-block barrier via LDS-aggregated
// arrival + one device atomicAdd; waves spin on counter (no fence).
__global__ __launch_bounds__(512, 2) void lstm_persist(
    const unsigned short* __restrict__ Xbf,
    unsigned short* __restrict__ h1bufs, unsigned short* __restrict__ h2bufs,
    const unsigned short* __restrict__ Bpack,
    const float* __restrict__ b1p, const float* __restrict__ b2p,
    unsigned int* __restrict__ cnts) {
  __shared__ __align__(16) unsigned short Abuf[4][2][64 * 64];  // 64 KB
  __shared__ __align__(16) float zt0[64 * 132];                 // 33 KB
  __shared__ __align__(16) float zt1[64 * 132];                 // 33 KB
  __shared__ unsigned int lds_arr;

  int bid = blockIdx.x;
  int layer = bid >> 7;
  int lid = bid & 127;
  // same (bid&7) => same XCD: co-locate one n-tile's 4 m-blocks (weight L2 reuse)
  int ntile = (lid & 7) | (((lid >> 5) & 3) << 3);
  int mtile = (lid >> 3) & 3;
  int m0 = mtile * 64;
  int u0 = ntile * 32;
  const int KG = layer ? 512 : 320;
  const int NIT = KG >> 6;   // 8 or 5

  int tid = threadIdx.x;
  int g = tid >> 7;           // k-group 0..3
  int wn = (tid >> 6) & 1;
  int lane = tid & 63;
  int gt = tid & 127;         // thread within k-group
  int kgbase = g * KG;
  unsigned int* cnt = cnts + mtile * 64;

  unsigned int SSu = layer ? SSU1 : SSU0;
  const unsigned short* bwave =
      Bpack + (layer ? LBU1 : 0u) + ntile * 8u * SSu + (unsigned)(g * 2 + wn) * SSu;

  if (tid == 0) lds_arr = 0u;

  // persistent cell state: thread -> (row m0+(tid>>3), units u0+(tid&7)*4)
  int rr_ = tid >> 3, ugc = tid & 7;
  int rgc = m0 + rr_;
  floatx4 creg = (floatx4){0.f, 0.f, 0.f, 0.f};
  const float* bpb = (layer ? b2p : b1p) + (size_t)(u0 + ugc * 4) * 4;
  floatx4 bpr[4];
  #pragma unroll
  for (int k = 0; k < 4; ++k) bpr[k] = *(const floatx4*)&bpb[k * 4];
  __syncthreads();

  ushort8 bc[2][4], bn[2][4], areg[4];

  for (int p = 0; p <= TT; ++p) {
    bool active = layer == 0 ? (p < TT) : (p >= 1);
    const unsigned short* hp1 = h1bufs + (size_t)(p & 1) * BBHH;
    const unsigned short* hp2 = h2bufs + (size_t)(p & 1) * BBHH;

    auto loadB = [&](ushort8 (&dst)[2][4], int it) {
      #pragma unroll
      for (int ksl = 0; ksl < 2; ++ksl)
        #pragma unroll
        for (int ni = 0; ni < 4; ++ni)
          dst[ksl][ni] = *(const ushort8*)(bwave +
              (unsigned)((it * 2 + ksl) * 4 + ni) * 512u + lane * 8);
    };
    // A chunk: 64 rows x 64 k. thread gt, pass c: row c*16+(gt>>3), quad gt&7.
    auto issueA = [&](int it) {
      int kb = kgbase + (it << 6);
      #pragma unroll
      for (int c = 0; c < 4; ++c) {
        int rg = m0 + c * 16 + (gt >> 3);
        int kq = gt & 7;
        if (layer == 0 && kb < DD) {
          areg[c] = *(const ushort8*)(Xbf + (size_t)rg * TD + p * DD + kb + kq * 8);
        } else if (layer == 0 && kb >= 1152) {
          areg[c] = (ushort8){0, 0, 0, 0, 0, 0, 0, 0};
        } else {
          const unsigned short* src;
          if (layer == 0)      src = hp1 + (size_t)rg * HH + (kb - DD) + kq * 8;
          else if (kb < HH)    src = hp1 + (size_t)rg * HH + kb + kq * 8;
          else                 src = hp2 + (size_t)rg * HH + (kb - HH) + kq * 8;
          union { unsigned long long u[2]; ushort8 v; } uu;
          uu.u[0] = __hip_atomic_load((const unsigned long long*)src,
                                      __ATOMIC_RELAXED, __HIP_MEMORY_SCOPE_AGENT);
          uu.u[1] = __hip_atomic_load((const unsigned long long*)(src + 4),
                                      __ATOMIC_RELAXED, __HIP_MEMORY_SCOPE_AGENT);
          areg[c] = uu.v;
        }
      }
    };
    auto commitA = [&](int buf) {
      unsigned short* dst = &Abuf[g][buf][0];
      #pragma unroll
      for (int c = 0; c < 4; ++c) {
        int row = c * 16 + (gt >> 3);
        int kq = gt & 7;
        *(ushort8*)&dst[row * 64 + ((kq ^ (row & 7)) << 3)] = areg[c];
      }
    };

    if (active) loadB(bc, 0);   // weights independent of h: hide under spin

    if (p > 0) {
      if (lane == 0) {
        unsigned int tgt = 64u * (unsigned)p;
        while (__hip_atomic_load(cnt, __ATOMIC_RELAXED, __HIP_MEMORY_SCOPE_AGENT) < tgt)
          __builtin_amdgcn_s_sleep(2);
      }
    }

    if (active) {
      floatx4 acc[4][4];
      #pragma unroll
      for (int i = 0; i < 4; ++i)
        #pragma unroll
        for (int j = 0; j < 4; ++j) acc[i][j] = (floatx4){0.f, 0.f, 0.f, 0.f};

      issueA(0);
      commitA(0);
      for (int it = 0; it < NIT; ++it) {
        int buf = it & 1;
        __syncthreads();   // group's chunk committed; both waves aligned
        if (it + 1 < NIT) { issueA(it + 1); loadB(bn, it + 1); }
        const unsigned short* Ab = &Abuf[g][buf][0];
        #pragma unroll
        for (int ksl = 0; ksl < 2; ++ksl) {
          int qb = ksl * 4 + (lane >> 4);
          short8 af[4];
          #pragma unroll
          for (int mi = 0; mi < 4; ++mi) {
            int ml = mi * 16 + (lane & 15);
            af[mi] = *(const short8*)&Ab[ml * 64 + ((qb ^ (ml & 7)) << 3)];
          }
          #pragma unroll
          for (int mi = 0; mi < 4; ++mi)
            #pragma unroll
            for (int ni = 0; ni < 4; ++ni)
              acc[mi][ni] = __builtin_amdgcn_mfma_f32_16x16x32_bf16(
                  af[mi], (short8)bc[ksl][ni], acc[mi][ni], 0, 0, 0);
        }
        if (it + 1 < NIT) {
          commitA(buf ^ 1);   // waits A loads (latency hidden under MFMA)
          #pragma unroll
          for (int ksl = 0; ksl < 2; ++ksl)
            #pragma unroll
            for (int ni = 0; ni < 4; ++ni) bc[ksl][ni] = bn[ksl][ni];
        }
      }
      __syncthreads();

      // ---- 4-partial reduction via zt0 (g0+g2) / zt1 (g1+g3) ----
      float* ztw = (g & 1) ? zt1 : zt0;
      if (g < 2) {
        #pragma unroll
        for (int mi = 0; mi < 4; ++mi)
          #pragma unroll
          for (int ni = 0; ni < 4; ++ni)
            #pragma unroll
            for (int rr = 0; rr < 4; ++rr) {
              int row = mi * 16 + (lane >> 4) * 4 + rr;
              int col = wn * 64 + ni * 16 + (lane & 15);
              ztw[row * 132 + col] = acc[mi][ni][rr];
            }
      }
      __syncthreads();
      if (g >= 2) {
        #pragma unroll
        for (int mi = 0; mi < 4; ++mi)
          #pragma unroll
          for (int ni = 0; ni < 4; ++ni)
            #pragma unroll
            for (int rr = 0; rr < 4; ++rr) {
              int row = mi * 16 + (lane >> 4) * 4 + rr;
              int col = wn * 64 + ni * 16 + (lane & 15);
              ztw[row * 132 + col] += acc[mi][ni][rr];
            }
      }
      __syncthreads();

      // ---- cell (c in registers), h -> L3 via agent-scope store ----
      unsigned short* hn = (layer ? h2bufs : h1bufs) + (size_t)((p + 1) & 1) * BBHH;
      ushort4v hv;
      #pragma unroll
      for (int k = 0; k < 4; ++k) {
        int cbase = rr_ * 132 + (ugc * 4 + k) * 4;
        floatx4 gt0 = *(const floatx4*)&zt0[cbase];
        floatx4 gt1 = *(const floatx4*)&zt1[cbase];
        float i_ = gt0[0] + gt1[0] + bpr[k][0];
        float j_ = gt0[1] + gt1[1] + bpr[k][1];
        float f_ = gt0[2] + gt1[2] + bpr[k][2] + 1.f;   // FORGET_BIAS
        float o_ = gt0[3] + gt1[3] + bpr[k][3];
        float nc = creg[k] * sigm(f_) + sigm(i_) * tanh_fast(j_);
        creg[k] = nc;
        hv[k] = f2bf(tanh_fast(nc) * sigm(o_));
      }
      union { ushort4v v; unsigned long long u; } hu;
      hu.v = hv;
      __hip_atomic_store((unsigned long long*)&hn[(size_t)rgc * HH + u0 + ugc * 4],
                         hu.u, __ATOMIC_RELAXED, __HIP_MEMORY_SCOPE_AGENT);
    }

    // ---- arrival: own stores drained -> LDS agg -> one device atomic ----
    asm volatile("s_waitcnt vmcnt(0)" ::: "memory");
    if (lane == 0) {
      unsigned int old = atomicAdd(&lds_arr, 1u);
      if (old == 8u * (unsigned)p + 7u) atomicAdd(cnt, 1u);
    }
  }
}

// ---------------- dense head + MSE loss (plain h2) ------------------------
__global__ __launch_bounds__(64) void head_loss(const unsigned short* __restrict__ h2,
                                                const float* __restrict__ Wd,
                                                const float* __restrict__ bd,
                                                const float* __restrict__ labels,
                                                float* __restrict__ out) {
  int b = blockIdx.x;
  int l = threadIdx.x;
  float pacc[24];
  #pragma unroll
  for (int n = 0; n < 24; ++n) pacc[n] = 0.f;
  for (int k = l; k < HH; k += 64) {
    float hv = bf2f(h2[(size_t)b * HH + k]);
    const float* wr = Wd + (size_t)k * 24;
    #pragma unroll
    for (int n = 0; n < 24; ++n) pacc[n] += hv * wr[n];
  }
  #pragma unroll
  for (int n = 0; n < 24; ++n) {
    float v = pacc[n];
    for (int off = 32; off > 0; off >>= 1) v += __shfl_down(v, off);
    pacc[n] = v;
  }
  if (l == 0) {
    float s = 0.f;
    #pragma unroll
    for (int n = 0; n < 24; ++n) {
      float pred = pacc[n] + bd[n];
      float d = pred - labels[b * 24 + n];
      s += d * d;
    }
    atomicAdd(out, s * (1.0f / 6144.0f));
  }
}

extern "C" void kernel_launch(void* const* d_in, const int* in_sizes, int n_in,
                              void* d_out, int out_size, void* d_ws, size_t ws_size,
                              hipStream_t stream) {
  const float* features = (const float*)d_in[0];
  const float* labels   = (const float*)d_in[1];
  const float* W1 = (const float*)d_in[2];
  const float* b1 = (const float*)d_in[3];
  const float* W2 = (const float*)d_in[4];
  const float* b2 = (const float*)d_in[5];
  const float* Wd = (const float*)d_in[6];
  const float* bd = (const float*)d_in[7];

  char* ws = (char*)d_ws;
  unsigned int*   cnts = (unsigned int*)(ws + OFF_CNT);
  float*          b1p  = (float*)(ws + OFF_B1P);
  float*          b2p  = (float*)(ws + OFF_B2P);
  unsigned short* h1   = (unsigned short*)(ws + OFF_H1);
  unsigned short* h2   = (unsigned short*)(ws + OFF_H2);
  unsigned short* Xbf  = (unsigned short*)(ws + OFF_X);
  unsigned short* BP   = (unsigned short*)(ws + OFF_BP);
  float* out = (float*)d_out;

  init_zero<<<528, 256, 0, stream>>>(out, (uint4*)ws, 135168L);
  feat2bf<<<5376, 256, 0, stream>>>(features, Xbf, 1376256L);
  bpack<<<3328, 256, 0, stream>>>(W1, W2, BP);
  bias_perm<<<32, 256, 0, stream>>>(b1, b2, b1p, b2p);

  void* args[] = {&Xbf, &h1, &h2, &BP, &b1p, &b2p, &cnts};
  hipLaunchCooperativeKernel((const void*)lstm_persist, dim3(256), dim3(512),
                             args, 0, stream);

  // final h2 is buffer (TT+1)&1 = 1
  head_loss<<<256, 64, 0, stream>>>(h2 + BBHH, Wd, bd, labels, out);
}